// Round 15
// baseline (216.049 us; speedup 1.0000x reference)
//
#include <hip/hip_runtime.h>
#include <hip/hip_fp16.h>

// Capsule routing via materialized fp16 u_hat (L3-resident), multi-kernel,
// plain stores only. Ledger: R1 coop grid.sync ~60us -> never. R2 contended
// atomics -> never. R3/R4 occupancy juggling on GEMM1 -> regress. R5/R12:
// XCD swizzle helps ONLY when dominant stream is shared. R8 fp16 split-K.
// R9 pk_fma. R11 materialized-U 216.7. R13 fusion 214.2. R14 c-pair-packed U
// 213.3 (flat -> not load-issue-bound). R12 counters: agree Occupancy 36% at
// 1 TB/s -> latency-bound, short on TLP (G1). R15: agree split over b-halves
// (960->1440 blocks, agg 2-slice split-K, wave-shfl reduction, LDS 8KB);
// gemvs c-sixteenths (640->1280 blocks, s split-K 16 slices). Arithmetic
// unchanged.
// B=256, K_IN=8, C=1152, J=10, D=16, 4 iters. n = j*16+d.

typedef float v2f __attribute__((ext_vector_type(2)));

#define C_IN  1152
#define J_U   10
#define M_DIM 9216
#define N_DIM 160
#define B_SZ  256

// ---- ws layout (float offsets); ws is 256 MiB = 67.1M floats ----
#define OFF_XT   0             // Xt[9216][256] fp32
#define OFF_U    2400000       // U uint2[160][576][128] = 94 MB
#define OFF_SP16 26000000      // s_part fp32 [16][160][256] (655K floats)
#define OFF_SP32 26700000      // s_part fp32 [32][160][256] (it0, from ubuild)
#define OFF_B0   28100000      // bij ping [1152][10]
#define OFF_B1   28120000      // bij pong [1152][10]
#define OFF_AG   28140000      // agg_part [2][1152][10] (b-half split-K)

// ================= prep: transpose x -> Xt (proven 64x64 tile) =================
__global__ __launch_bounds__(256) void k_prep(const float* __restrict__ x,
                                              float* __restrict__ Xt) {
    __shared__ float T[64][65];
    const int bid = blockIdx.x, t = threadIdx.x;
    const int m0 = (bid % 144) * 64, b0 = (bid / 144) * 64;
    {
        const int b_l = t >> 2, q = t & 3;
        const float* xp = x + (size_t)(b0 + b_l) * M_DIM + m0 + q * 16;
#pragma unroll
        for (int u = 0; u < 4; ++u) {
            const float4 v = *reinterpret_cast<const float4*>(xp + 4 * u);
            T[q * 16 + 4 * u + 0][b_l] = v.x;
            T[q * 16 + 4 * u + 1][b_l] = v.y;
            T[q * 16 + 4 * u + 2][b_l] = v.z;
            T[q * 16 + 4 * u + 3][b_l] = v.w;
        }
    }
    __syncthreads();
    {
        const int m_l = t >> 2, q = t & 3;
        float4* op = reinterpret_cast<float4*>(Xt + (size_t)(m0 + m_l) * B_SZ + b0 + q * 16);
#pragma unroll
        for (int u = 0; u < 4; ++u)
            op[u] = make_float4(T[m_l][q * 16 + 4 * u], T[m_l][q * 16 + 4 * u + 1],
                                T[m_l][q * 16 + 4 * u + 2], T[m_l][q * 16 + 4 * u + 3]);
    }
}

// ===== ubuild: U[n][cp][b2] (c-pair uint2) = sum_k W*Xt; also s0 split-K ========
// 512 blocks = 32 c-chunks(36) x 16 n-chunks(10), LINEAR mapping. (R14, proven)
__global__ __launch_bounds__(256) void k_ubuild(const float* __restrict__ Xt,
                                                const float* __restrict__ W,
                                                uint2* __restrict__ U4,
                                                float* __restrict__ s32) {
    __shared__ float Wl[2880];                 // [36 c][10 n][8 k]
    __shared__ v2f Sred[2][10][128];
    const int cc = blockIdx.x >> 4, nc = blockIdx.x & 15;
    const int c0 = cc * 36, n0 = nc * 10;
    const int t = threadIdx.x;
    const float4* W4 = reinterpret_cast<const float4*>(W);
    float4* Wl4 = reinterpret_cast<float4*>(Wl);
    for (int i = t; i < 720; i += 256) {       // 36 c x 10 n x 2 float4
        const int c = i / 20, r = i - c * 20;
        const int n = r >> 1, half = r & 1;
        Wl4[i] = W4[(size_t)(c0 + c) * 320 + (n0 + n) * 2 + half];
    }
    __syncthreads();
    const int b2 = t & 127, ch = t >> 7;
    v2f sacc[10] = {};
    for (int cp = 0; cp < 9; ++cp) {
        const int ca = ch * 18 + 2 * cp;       // local c (even)
        v2f xa[8], xb[8];
#pragma unroll
        for (int k = 0; k < 8; ++k) {
            xa[k] = *reinterpret_cast<const v2f*>(
                Xt + (size_t)(k * C_IN + c0 + ca) * B_SZ + 2 * b2);
            xb[k] = *reinterpret_cast<const v2f*>(
                Xt + (size_t)(k * C_IN + c0 + ca + 1) * B_SZ + 2 * b2);
        }
        const int cpg = (c0 + ca) >> 1;        // global c-pair index
#pragma unroll
        for (int n = 0; n < 10; ++n) {
            v2f acca = {0.f, 0.f}, accb = {0.f, 0.f};
            const float* wa = &Wl[(ca * 10 + n) * 8];
            const float* wb = &Wl[((ca + 1) * 10 + n) * 8];
#pragma unroll
            for (int k = 0; k < 8; ++k) {
                acca += xa[k] * (v2f){wa[k], wa[k]};   // v_pk_fma_f32
                accb += xb[k] * (v2f){wb[k], wb[k]};
            }
            const __half2 ha = __floats2half2_rn(acca.x, acca.y);
            const __half2 hb = __floats2half2_rn(accb.x, accb.y);
            uint2 st;
            st.x = *reinterpret_cast<const unsigned*>(&ha);
            st.y = *reinterpret_cast<const unsigned*>(&hb);
            U4[((size_t)(n0 + n) * 576 + cpg) * 128 + b2] = st;
            sacc[n] += acca + accb;
        }
    }
#pragma unroll
    for (int n = 0; n < 10; ++n) Sred[ch][n][b2] = sacc[n];
    __syncthreads();
    for (int i = t; i < 1280; i += 256) {      // 10 n x 128 b-pairs
        const int n = i >> 7, bi = i & 127;
        const v2f s = Sred[0][n][bi] + Sred[1][n][bi];
        *reinterpret_cast<float2*>(
            s32 + ((size_t)cc * N_DIM + n0 + n) * B_SZ + 2 * bi) =
            make_float2(0.1f * s.x, 0.1f * s.y);
    }
}

// ================= gemvs: s[n][b] = sum_c csm[c,j(n)] * U[n][c][b] ===============
// 1280 blocks = 16 c-sixteenths(72) x 80 n-pairs. Prologue sums the 2-slice
// agg split-K. nobij: b = agg only (it1). Thread = (b-pair, n-half); 36 cp loads.
__global__ __launch_bounds__(256) void k_gemvs(const uint2* __restrict__ U4,
                                               const float* __restrict__ bij_old,
                                               float* __restrict__ bij_new,
                                               const float* __restrict__ agg_part,
                                               float* __restrict__ s_part,
                                               int nobij) {
    __shared__ float braw[720];
    __shared__ float csm[72];
    const int ce = blockIdx.x / 80, np = blockIdx.x % 80;
    const int c0 = ce * 72, n0 = np * 2, j = np >> 3;   // n-pair never crosses j
    const int t = threadIdx.x;
    for (int i = t; i < 720; i += 256) {
        float v = agg_part[c0 * J_U + i] + agg_part[11520 + c0 * J_U + i];
        if (!nobij) v += bij_old[c0 * J_U + i];
        braw[i] = v;
        if (np == 0) bij_new[c0 * J_U + i] = v;   // duplicates benign
    }
    __syncthreads();
    if (t < 72) {
        const int r0 = t * J_U;
        float mx = -1e30f;
#pragma unroll
        for (int q = 0; q < J_U; ++q) mx = fmaxf(mx, braw[r0 + q]);
        float sum = 0.f;
#pragma unroll
        for (int q = 0; q < J_U; ++q) sum += __expf(braw[r0 + q] - mx);
        csm[t] = __expf(braw[r0 + j] - mx) / sum;
    }
    __syncthreads();
    const int b2 = t & 127, nh = t >> 7;
    const int nn = n0 + nh;
    const uint2* up = U4 + ((size_t)nn * 576 + ce * 36) * 128 + b2;
    v2f acc = {0.f, 0.f};
#pragma unroll 6
    for (int cp = 0; cp < 36; ++cp) {
        const uint2 u = up[(size_t)cp * 128];
        const float2 fa = __half22float2(reinterpret_cast<const __half2&>(u.x));
        const float2 fb = __half22float2(reinterpret_cast<const __half2&>(u.y));
        const float ca_ = csm[2 * cp], cb_ = csm[2 * cp + 1];
        acc += (v2f){ca_, ca_} * (v2f){fa.x, fa.y};    // v_pk_fma_f32
        acc += (v2f){cb_, cb_} * (v2f){fb.x, fb.y};
    }
    *reinterpret_cast<float2*>(s_part + (size_t)ce * 40960 + (size_t)nn * B_SZ + 2 * b2) =
        make_float2(acc.x, acc.y);
}

// ================= agree: agg[c,j] = sum_{b,d} U[j*16+d][c][b] * v[b,d] =========
// 1440 blocks = 10 j x 72 cc(16 c) x 2 b-halves, LINEAR mapping. Prologue:
// reduce NSL s-slices + squash for 128 b (this half) -> v in LDS (8KB).
// Main: wave ch owns 2 c-pairs; b-reduction = pure 64-lane shfl (no LDS).
// agg written as 2-slice split-K [bh][1152][10].
template <int NSL>
__global__ __launch_bounds__(256) void k_agree(const uint2* __restrict__ U4,
                                               const float* __restrict__ s_base,
                                               float* __restrict__ agg_part) {
    __shared__ float sv[16 * 128];                 // [d][b-local]
    const int bid = blockIdx.x;
    const int j = bid / 144;                       // 144 = 72 cc x 2 bh
    const int r = bid % 144;
    const int cc = r >> 1, bh = r & 1;
    const int c0 = cc * 16;
    const int t = threadIdx.x;
    for (int i = t; i < 2048; i += 256) {          // reduce slices, +1e-5 (ref order)
        const int d = i >> 7, b = i & 127;
        const float* p = s_base + (size_t)(j * 16 + d) * B_SZ + bh * 128 + b;
        float s = 1e-5f;
#pragma unroll
        for (int ce = 0; ce < NSL; ++ce) s += p[(size_t)ce * 40960];
        sv[d * 128 + b] = s;
    }
    __syncthreads();
    if (t < 128) {                                 // squash per b (d-range complete)
        float mag = 0.f;
#pragma unroll
        for (int d = 0; d < 16; ++d) { const float xx = sv[d * 128 + t]; mag += xx * xx; }
        const float sc = sqrtf(mag) / (1.f + mag);
#pragma unroll
        for (int d = 0; d < 16; ++d) sv[d * 128 + t] *= sc;
    }
    __syncthreads();
    const int ch = t >> 6, b2 = t & 63;            // wave = ch, lane = b2
    float acc[4] = {};                             // 4 c's = 2 c-pairs
#pragma unroll
    for (int cp = 0; cp < 2; ++cp) {
        const int cpg = (c0 >> 1) + ch * 2 + cp;   // global c-pair
        const uint2* up = U4 + ((size_t)(j * 16) * 576 + cpg) * 128 + bh * 64 + b2;
#pragma unroll
        for (int d = 0; d < 16; ++d) {
            const uint2 u = up[(size_t)d * 576 * 128];
            const float2 fa = __half22float2(reinterpret_cast<const __half2&>(u.x));
            const float2 fb = __half22float2(reinterpret_cast<const __half2&>(u.y));
            const float2 vv = *reinterpret_cast<const float2*>(&sv[d * 128 + 2 * b2]);
            acc[2 * cp]     += fa.x * vv.x + fa.y * vv.y;
            acc[2 * cp + 1] += fb.x * vv.x + fb.y * vv.y;
        }
    }
#pragma unroll
    for (int ci = 0; ci < 4; ++ci)                 // 64-lane butterfly per c
#pragma unroll
        for (int off = 32; off > 0; off >>= 1) acc[ci] += __shfl_down(acc[ci], off);
    if (b2 == 0) {
#pragma unroll
        for (int ci = 0; ci < 4; ++ci)             // c = c0 + ch*4 + ci
            agg_part[(size_t)bh * 11520 + (size_t)(c0 + ch * 4 + ci) * J_U + j] = acc[ci];
    }
}

// ================= sqout: final squash (16-slice s_part) -> out =================
__global__ __launch_bounds__(256) void k_sqout(const float* __restrict__ s_part,
                                               float* __restrict__ out) {
    __shared__ float sl[16 * 32];
    const int j = blockIdx.x >> 3, bc = blockIdx.x & 7;
    const int b0 = bc * 32;
    const int t = threadIdx.x;
    for (int i = t; i < 512; i += 256) {
        const int d = i >> 5, bl = i & 31;
        const float* p = s_part + (size_t)(j * 16 + d) * B_SZ + b0 + bl;
        float s = 1e-5f;
#pragma unroll
        for (int ce = 0; ce < 16; ++ce) s += p[(size_t)ce * 40960];
        sl[d * 32 + bl] = s;
    }
    __syncthreads();
    if (t < 32) {
        float mag = 0.f;
#pragma unroll
        for (int d = 0; d < 16; ++d) { const float xx = sl[d * 32 + t]; mag += xx * xx; }
        const float sc = sqrtf(mag) / (1.f + mag);
#pragma unroll
        for (int d = 0; d < 16; ++d)
            out[(size_t)(b0 + t) * N_DIM + j * 16 + d] = sl[d * 32 + t] * sc;
    }
}

extern "C" void kernel_launch(void* const* d_in, const int* in_sizes, int n_in,
                              void* d_out, int out_size, void* d_ws, size_t ws_size,
                              hipStream_t stream) {
    const float* x = (const float*)d_in[0];   // (256, 8, 1152) fp32
    const float* W = (const float*)d_in[1];   // (1, 1152, 10, 16, 8) fp32
    float* out = (float*)d_out;               // (256, 10, 16, 1) fp32
    float* ws  = (float*)d_ws;
    float* Xt   = ws + OFF_XT;
    uint2* U4   = (uint2*)(ws + OFF_U);
    float* sp16 = ws + OFF_SP16;
    float* sp32 = ws + OFF_SP32;
    float* bij0 = ws + OFF_B0;
    float* bij1 = ws + OFF_B1;
    float* agg  = ws + OFF_AG;

    k_prep<<<576, 256, 0, stream>>>(x, Xt);
    k_ubuild<<<512, 256, 0, stream>>>(Xt, W, U4, sp32);             // U + s0 (csm=0.1)
    k_agree<32><<<1440, 256, 0, stream>>>(U4, sp32, agg);           // v0 -> agg0 (2-slice)
    k_gemvs<<<1280, 256, 0, stream>>>(U4, bij1, bij0, agg, sp16, 1); // b1=agg0, s1
    k_agree<16><<<1440, 256, 0, stream>>>(U4, sp16, agg);           // v1 -> agg1
    k_gemvs<<<1280, 256, 0, stream>>>(U4, bij0, bij1, agg, sp16, 0); // b2, s2
    k_agree<16><<<1440, 256, 0, stream>>>(U4, sp16, agg);           // v2 -> agg2
    k_gemvs<<<1280, 256, 0, stream>>>(U4, bij1, bij0, agg, sp16, 0); // b3, s3 (bn dead)
    k_sqout<<<80, 256, 0, stream>>>(sp16, out);                     // v3 -> out
}